// Round 1
// baseline (7858.138 us; speedup 1.0000x reference)
//
#include <hip/hip_runtime.h>
#include <math.h>

// Problem constants
#define B_  8
#define N_  1024
#define C_  12
#define E_  256
#define H_  8
#define D_  32      // E/H
#define L_  4
#define XE_ 1024    // X*E
#define NC_ 5
#define S_  1025    // N+1
#define M_  8200    // B*S
#define EPS_ 1e-5f

// ---------------- Embedding: x@W_emb+b -> LN -> GELU; cls row raw ----------
__global__ void embed_kernel(const float* __restrict__ x, const float* __restrict__ Wemb,
                             const float* __restrict__ bemb, const float* __restrict__ g,
                             const float* __restrict__ be, const float* __restrict__ cls,
                             float* __restrict__ h)
{
    int t = blockIdx.x;            // 0..M_-1
    int b = t / S_, s = t % S_;
    int e = threadIdx.x;           // 0..255
    __shared__ float xs[16];
    __shared__ float red[256];

    if (s == 0) {                  // cls token, raw copy (pos added per layer)
        h[(long)t * E_ + e] = cls[e];
        return;
    }
    int n = s - 1;
    if (e < C_) xs[e] = x[((long)b * N_ + n) * C_ + e];
    __syncthreads();

    float acc = bemb[e];
#pragma unroll
    for (int c = 0; c < C_; ++c) acc += xs[c] * Wemb[c * E_ + e];

    // LayerNorm over E
    red[e] = acc; __syncthreads();
    for (int st = 128; st; st >>= 1) { if (e < st) red[e] += red[e + st]; __syncthreads(); }
    float mean = red[0] * (1.0f / E_); __syncthreads();
    float d = acc - mean;
    red[e] = d * d; __syncthreads();
    for (int st = 128; st; st >>= 1) { if (e < st) red[e] += red[e + st]; __syncthreads(); }
    float var = red[0] * (1.0f / E_);
    float ln = d * rsqrtf(var + EPS_) * g[e] + be[e];
    float gel = 0.5f * ln * (1.0f + erff(ln * 0.70710678118f));
    h[(long)t * E_ + e] = gel;
}

// --------------- (optional +pos into h) then LayerNorm -> y ----------------
__global__ void ln_kernel(float* __restrict__ h, const float* __restrict__ pos,
                          const float* __restrict__ g, const float* __restrict__ bb,
                          float* __restrict__ y)
{
    int t = blockIdx.x;            // token index
    int s = t % S_;
    int e = threadIdx.x;
    long idx = (long)t * E_ + e;
    __shared__ float red[256];

    float v = h[idx];
    if (pos) { v += pos[(long)s * E_ + e]; h[idx] = v; }

    red[e] = v; __syncthreads();
    for (int st = 128; st; st >>= 1) { if (e < st) red[e] += red[e + st]; __syncthreads(); }
    float mean = red[0] * (1.0f / E_); __syncthreads();
    float d = v - mean;
    red[e] = d * d; __syncthreads();
    for (int st = 128; st; st >>= 1) { if (e < st) red[e] += red[e + st]; __syncthreads(); }
    float var = red[0] * (1.0f / E_);
    y[idx] = d * rsqrtf(var + EPS_) * g[e] + bb[e];
}

// --------------- Tiled GEMM: out = act(A@W + bias) [+ res] ----------------
// A: [M,K], W: [K,N], act: 0=none, 1=exact GELU. res nullable ([M,N]).
#define TS 32
__global__ void gemm_kernel(const float* __restrict__ A, const float* __restrict__ W,
                            const float* __restrict__ bias, const float* __restrict__ res,
                            float* __restrict__ out, int M, int K, int N, int act)
{
    __shared__ float As[TS][TS + 1];
    __shared__ float Ws[TS][TS + 1];
    int tx = threadIdx.x, ty = threadIdx.y;       // 16x16
    int tid = ty * 16 + tx;
    int row0 = blockIdx.y * TS;
    int col0 = blockIdx.x * TS;
    float acc00 = 0.f, acc01 = 0.f, acc10 = 0.f, acc11 = 0.f;

    for (int k0 = 0; k0 < K; k0 += TS) {
        for (int i = tid; i < TS * TS; i += 256) {
            int r = i / TS, c = i % TS;
            int gr = row0 + r;
            As[r][c] = (gr < M) ? A[(long)gr * K + k0 + c] : 0.f;
            Ws[r][c] = W[(long)(k0 + r) * N + col0 + c];
        }
        __syncthreads();
#pragma unroll
        for (int kk = 0; kk < TS; ++kk) {
            float a0 = As[ty * 2 + 0][kk];
            float a1 = As[ty * 2 + 1][kk];
            float w0 = Ws[kk][tx * 2 + 0];
            float w1 = Ws[kk][tx * 2 + 1];
            acc00 += a0 * w0; acc01 += a0 * w1;
            acc10 += a1 * w0; acc11 += a1 * w1;
        }
        __syncthreads();
    }

    float accs[2][2] = {{acc00, acc01}, {acc10, acc11}};
#pragma unroll
    for (int i = 0; i < 2; ++i) {
        int r = row0 + ty * 2 + i;
        if (r >= M) continue;
#pragma unroll
        for (int j = 0; j < 2; ++j) {
            int c = col0 + tx * 2 + j;
            float v = accs[i][j] + bias[c];
            if (act == 1) v = 0.5f * v * (1.0f + erff(v * 0.70710678118f));
            if (res) v += res[(long)r * N + c];
            out[(long)r * N + c] = v;
        }
    }
}

// --------------- Attention: one wave per query row -------------------------
// q,k,v: [B,S,H,D] (row-major, e = h*D+d). softmax over keys, THEN /16.
__global__ void attn_kernel(const float* __restrict__ q, const float* __restrict__ k,
                            const float* __restrict__ v, float* __restrict__ o)
{
    __shared__ float sc[4][S_];
    __shared__ float qs[4][D_];
    int wid = threadIdx.x >> 6;
    int lane = threadIdx.x & 63;
    int gq = blockIdx.x * 4 + wid;       // exact: grid*4 == B*H*S
    int qpos = gq % S_;
    int bh = gq / S_;
    int b = bh / H_, hh = bh % H_;

    const float* qrow = q + ((long)((long)b * S_ + qpos) * H_ + hh) * D_;
    if (lane < D_) qs[wid][lane] = qrow[lane];
    __syncthreads();

    const float* kbase = k + ((long)b * S_ * H_ + hh) * D_;
    float mx = -1e30f;
    for (int j = lane; j < S_; j += 64) {
        const float* kr = kbase + (long)j * H_ * D_;
        float s = 0.f;
#pragma unroll
        for (int d = 0; d < D_; ++d) s += qs[wid][d] * kr[d];
        sc[wid][j] = s;
        mx = fmaxf(mx, s);
    }
#pragma unroll
    for (int off = 32; off; off >>= 1) mx = fmaxf(mx, __shfl_xor(mx, off));
    __syncthreads();

    float sum = 0.f;
    for (int j = lane; j < S_; j += 64) {
        float e = expf(sc[wid][j] - mx);
        sc[wid][j] = e;
        sum += e;
    }
#pragma unroll
    for (int off = 32; off; off >>= 1) sum += __shfl_xor(sum, off);
    float inv = 1.0f / (sum * 16.0f);    // div sqrt(E)=16 AFTER softmax
    __syncthreads();

    const float* vbase = v + ((long)b * S_ * H_ + hh) * D_;
    if (lane < D_) {
        float acc = 0.f;
        for (int j = 0; j < S_; ++j) acc += sc[wid][j] * vbase[(long)j * H_ * D_ + lane];
        o[((long)((long)b * S_ + qpos) * H_ + hh) * D_ + lane] = acc * inv;
    }
}

// --------------- Classifier: mean-pool -> Linear -> LN -> Linear ----------
__global__ void cls_kernel(const float* __restrict__ h, const float* __restrict__ Wc1,
                           const float* __restrict__ bc1, const float* __restrict__ lg,
                           const float* __restrict__ lb, const float* __restrict__ Wc2,
                           const float* __restrict__ bc2, float* __restrict__ out)
{
    int b = blockIdx.x;
    int e = threadIdx.x;
    __shared__ float p[256];
    __shared__ float red[256];
    __shared__ float lnv[256];

    float acc = 0.f;
    for (int s = 0; s < S_; ++s) acc += h[((long)b * S_ + s) * E_ + e];
    p[e] = acc * (1.0f / S_);
    __syncthreads();

    float c1 = bc1[e];
    for (int kk = 0; kk < E_; ++kk) c1 += p[kk] * Wc1[kk * E_ + e];

    red[e] = c1; __syncthreads();
    for (int st = 128; st; st >>= 1) { if (e < st) red[e] += red[e + st]; __syncthreads(); }
    float mean = red[0] * (1.0f / E_); __syncthreads();
    float d = c1 - mean;
    red[e] = d * d; __syncthreads();
    for (int st = 128; st; st >>= 1) { if (e < st) red[e] += red[e + st]; __syncthreads(); }
    float var = red[0] * (1.0f / E_);
    lnv[e] = d * rsqrtf(var + EPS_) * lg[e] + lb[e];
    __syncthreads();

    if (e < NC_) {
        float oacc = bc2[e];
        for (int kk = 0; kk < E_; ++kk) oacc += lnv[kk] * Wc2[kk * NC_ + e];
        out[b * NC_ + e] = oacc;
    }
}

extern "C" void kernel_launch(void* const* d_in, const int* in_sizes, int n_in,
                              void* d_out, int out_size, void* d_ws, size_t ws_size,
                              hipStream_t stream)
{
    const float* x      = (const float*)d_in[0];
    const float* W_emb  = (const float*)d_in[1];
    const float* b_emb  = (const float*)d_in[2];
    const float* g_emb  = (const float*)d_in[3];
    const float* be_emb = (const float*)d_in[4];
    const float* cls    = (const float*)d_in[5];
    const float* pos    = (const float*)d_in[6];
    const float* ln1_g  = (const float*)d_in[7];
    const float* ln1_b  = (const float*)d_in[8];
    const float* Wq     = (const float*)d_in[9];
    const float* bq     = (const float*)d_in[10];
    const float* Wk     = (const float*)d_in[11];
    const float* bk     = (const float*)d_in[12];
    const float* Wv     = (const float*)d_in[13];
    const float* bv     = (const float*)d_in[14];
    const float* Wo     = (const float*)d_in[15];
    const float* bo     = (const float*)d_in[16];
    const float* ln2_g  = (const float*)d_in[17];
    const float* ln2_b  = (const float*)d_in[18];
    const float* W1     = (const float*)d_in[19];
    const float* b1     = (const float*)d_in[20];
    const float* W2     = (const float*)d_in[21];
    const float* b2     = (const float*)d_in[22];
    const float* Wc1    = (const float*)d_in[23];
    const float* bc1    = (const float*)d_in[24];
    const float* lnc_g  = (const float*)d_in[25];
    const float* lnc_b  = (const float*)d_in[26];
    const float* Wc2    = (const float*)d_in[27];
    const float* bc2    = (const float*)d_in[28];
    float* out = (float*)d_out;

    float* ws = (float*)d_ws;
    float* h  = ws;                  // M_*E_
    float* y  = h  + (long)M_ * E_;  // M_*E_
    float* qb = y  + (long)M_ * E_;
    float* kb = qb + (long)M_ * E_;
    float* vb = kb + (long)M_ * E_;
    float* ob = vb + (long)M_ * E_;
    float* tb = ob + (long)M_ * E_;  // M_*XE_

    dim3 blk2(16, 16);
    dim3 gEE((E_ + TS - 1) / TS, (M_ + TS - 1) / TS);    // (8, 257)
    dim3 gEX((XE_ + TS - 1) / TS, (M_ + TS - 1) / TS);   // (32, 257)

    embed_kernel<<<M_, 256, 0, stream>>>(x, W_emb, b_emb, g_emb, be_emb, cls, h);

    for (int l = 0; l < L_; ++l) {
        // h += pos; y = LN1(h)
        ln_kernel<<<M_, 256, 0, stream>>>(h, pos, ln1_g + l * E_, ln1_b + l * E_, y);
        // Q, K, V
        gemm_kernel<<<gEE, blk2, 0, stream>>>(y, Wq + (long)l * E_ * E_, bq + l * E_, nullptr, qb, M_, E_, E_, 0);
        gemm_kernel<<<gEE, blk2, 0, stream>>>(y, Wk + (long)l * E_ * E_, bk + l * E_, nullptr, kb, M_, E_, E_, 0);
        gemm_kernel<<<gEE, blk2, 0, stream>>>(y, Wv + (long)l * E_ * E_, bv + l * E_, nullptr, vb, M_, E_, E_, 0);
        // attention
        attn_kernel<<<(B_ * H_ * S_) / 4, 256, 0, stream>>>(qb, kb, vb, ob);
        // h = h + o@Wo + bo
        gemm_kernel<<<gEE, blk2, 0, stream>>>(ob, Wo + (long)l * E_ * E_, bo + l * E_, h, h, M_, E_, E_, 0);
        // y = LN2(h); t = GELU(y@W1+b1); h = h + t@W2+b2
        ln_kernel<<<M_, 256, 0, stream>>>(h, nullptr, ln2_g + l * E_, ln2_b + l * E_, y);
        gemm_kernel<<<gEX, blk2, 0, stream>>>(y, W1 + (long)l * E_ * XE_, b1 + l * XE_, nullptr, tb, M_, E_, XE_, 1);
        gemm_kernel<<<gEE, blk2, 0, stream>>>(tb, W2 + (long)l * XE_ * E_, b2 + l * E_, h, h, M_, XE_, E_, 0);
    }

    cls_kernel<<<B_, 256, 0, stream>>>(h, Wc1, bc1, lnc_g, lnc_b, Wc2, bc2, out);
}

// Round 2
// 4746.146 us; speedup vs baseline: 1.6557x; 1.6557x over previous
//
#include <hip/hip_runtime.h>
#include <math.h>

// Problem constants
#define B_  8
#define N_  1024
#define C_  12
#define E_  256
#define H_  8
#define D_  32      // E/H
#define L_  4
#define XE_ 1024    // X*E
#define NC_ 5
#define S_  1025    // N+1
#define M_  8200    // B*S
#define EPS_ 1e-5f

// ---------------- Embedding: x@W_emb+b -> LN -> GELU; cls row raw ----------
__global__ void embed_kernel(const float* __restrict__ x, const float* __restrict__ Wemb,
                             const float* __restrict__ bemb, const float* __restrict__ g,
                             const float* __restrict__ be, const float* __restrict__ cls,
                             float* __restrict__ h)
{
    int t = blockIdx.x;            // 0..M_-1
    int b = t / S_, s = t % S_;
    int e = threadIdx.x;           // 0..255
    __shared__ float xs[16];
    __shared__ float red[256];

    if (s == 0) {                  // cls token, raw copy (pos added per layer)
        h[(long)t * E_ + e] = cls[e];
        return;
    }
    int n = s - 1;
    if (e < C_) xs[e] = x[((long)b * N_ + n) * C_ + e];
    __syncthreads();

    float acc = bemb[e];
#pragma unroll
    for (int c = 0; c < C_; ++c) acc += xs[c] * Wemb[c * E_ + e];

    // LayerNorm over E
    red[e] = acc; __syncthreads();
    for (int st = 128; st; st >>= 1) { if (e < st) red[e] += red[e + st]; __syncthreads(); }
    float mean = red[0] * (1.0f / E_); __syncthreads();
    float d = acc - mean;
    red[e] = d * d; __syncthreads();
    for (int st = 128; st; st >>= 1) { if (e < st) red[e] += red[e + st]; __syncthreads(); }
    float var = red[0] * (1.0f / E_);
    float ln = d * rsqrtf(var + EPS_) * g[e] + be[e];
    float gel = 0.5f * ln * (1.0f + erff(ln * 0.70710678118f));
    h[(long)t * E_ + e] = gel;
}

// --------------- (optional +pos into h) then LayerNorm -> y ----------------
__global__ void ln_kernel(float* __restrict__ h, const float* __restrict__ pos,
                          const float* __restrict__ g, const float* __restrict__ bb,
                          float* __restrict__ y)
{
    int t = blockIdx.x;            // token index
    int s = t % S_;
    int e = threadIdx.x;
    long idx = (long)t * E_ + e;
    __shared__ float red[256];

    float v = h[idx];
    if (pos) { v += pos[(long)s * E_ + e]; h[idx] = v; }

    red[e] = v; __syncthreads();
    for (int st = 128; st; st >>= 1) { if (e < st) red[e] += red[e + st]; __syncthreads(); }
    float mean = red[0] * (1.0f / E_); __syncthreads();
    float d = v - mean;
    red[e] = d * d; __syncthreads();
    for (int st = 128; st; st >>= 1) { if (e < st) red[e] += red[e + st]; __syncthreads(); }
    float var = red[0] * (1.0f / E_);
    y[idx] = d * rsqrtf(var + EPS_) * g[e] + bb[e];
}

// --------------- Tiled GEMM: out = act(A@W + bias) [+ res] ----------------
// A: [M,K], W: [K,N], act: 0=none, 1=exact GELU. res nullable ([M,N]).
#define TS 32
__global__ void gemm_kernel(const float* __restrict__ A, const float* __restrict__ W,
                            const float* __restrict__ bias, const float* __restrict__ res,
                            float* __restrict__ out, int M, int K, int N, int act)
{
    __shared__ float As[TS][TS + 1];
    __shared__ float Ws[TS][TS + 1];
    int tx = threadIdx.x, ty = threadIdx.y;       // 16x16
    int tid = ty * 16 + tx;
    int row0 = blockIdx.y * TS;
    int col0 = blockIdx.x * TS;
    float acc00 = 0.f, acc01 = 0.f, acc10 = 0.f, acc11 = 0.f;

    for (int k0 = 0; k0 < K; k0 += TS) {
        for (int i = tid; i < TS * TS; i += 256) {
            int r = i / TS, c = i % TS;
            int gr = row0 + r;
            As[r][c] = (gr < M) ? A[(long)gr * K + k0 + c] : 0.f;
            Ws[r][c] = W[(long)(k0 + r) * N + col0 + c];
        }
        __syncthreads();
#pragma unroll
        for (int kk = 0; kk < TS; ++kk) {
            float a0 = As[ty * 2 + 0][kk];
            float a1 = As[ty * 2 + 1][kk];
            float w0 = Ws[kk][tx * 2 + 0];
            float w1 = Ws[kk][tx * 2 + 1];
            acc00 += a0 * w0; acc01 += a0 * w1;
            acc10 += a1 * w0; acc11 += a1 * w1;
        }
        __syncthreads();
    }

    float accs[2][2] = {{acc00, acc01}, {acc10, acc11}};
#pragma unroll
    for (int i = 0; i < 2; ++i) {
        int r = row0 + ty * 2 + i;
        if (r >= M) continue;
#pragma unroll
        for (int j = 0; j < 2; ++j) {
            int c = col0 + tx * 2 + j;
            float v = accs[i][j] + bias[c];
            if (act == 1) v = 0.5f * v * (1.0f + erff(v * 0.70710678118f));
            if (res) v += res[(long)r * N + c];
            out[(long)r * N + c] = v;
        }
    }
}

// --------------- Flash attention: 64-query tile per block ------------------
// q,k,v: [B,S,H,D]. softmax over keys, THEN /16 (folded into final norm).
#define TQ 64
#define TK 64
#define NQT 17   // ceil(S_/TQ)
__global__ __launch_bounds__(256) void flash_attn_kernel(
    const float* __restrict__ q, const float* __restrict__ k,
    const float* __restrict__ v, float* __restrict__ o)
{
    __shared__ float Qs[TQ][33];      // pad 33: conflict-free scalar reads
    __shared__ float Ks[TK][33];
    __shared__ float Vs[TK][36];      // pad 36: 16B-aligned float4 reads
    __shared__ float Ss[TQ][65];
    __shared__ float alpha_s[TQ];
    __shared__ float l_s[TQ];

    int tid = threadIdx.x;
    int bh = blockIdx.x / NQT;
    int qt = blockIdx.x % NQT;
    int b = bh / H_, hh = bh % H_;
    int q0 = qt * TQ;

    const float* qbase = q + ((long)b * S_ * H_ + hh) * D_;
    const float* kbase = k + ((long)b * S_ * H_ + hh) * D_;
    const float* vbase = v + ((long)b * S_ * H_ + hh) * D_;

    // stage Q tile
    for (int i = tid; i < TQ * 8; i += 256) {
        int r = i >> 3, c4 = (i & 7) * 4;
        int gr = q0 + r;
        float4 val = make_float4(0.f, 0.f, 0.f, 0.f);
        if (gr < S_) val = *(const float4*)(qbase + (long)gr * (H_ * D_) + c4);
        Qs[r][c4 + 0] = val.x; Qs[r][c4 + 1] = val.y;
        Qs[r][c4 + 2] = val.z; Qs[r][c4 + 3] = val.w;
    }

    int ty = tid >> 4, tx = tid & 15;   // score micro-tile mapping (4x4)
    int rr = tid >> 2, dq = tid & 3;    // PV mapping: row rr, 8 d-cols at dq*8
    float o_acc[8];
#pragma unroll
    for (int i = 0; i < 8; ++i) o_acc[i] = 0.f;
    float m_i = -1e30f, l_i = 0.f;      // live only in tid<64

    for (int kt = 0; kt < NQT; ++kt) {
        int j0 = kt * TK;
        __syncthreads();                 // prev-iter readers of Ks/Vs/Ss done
        for (int i = tid; i < TK * 8; i += 256) {
            int r = i >> 3, c4 = (i & 7) * 4;
            int gr = j0 + r;
            float4 kv = make_float4(0.f, 0.f, 0.f, 0.f);
            float4 vv = make_float4(0.f, 0.f, 0.f, 0.f);
            if (gr < S_) {
                kv = *(const float4*)(kbase + (long)gr * (H_ * D_) + c4);
                vv = *(const float4*)(vbase + (long)gr * (H_ * D_) + c4);
            }
            Ks[r][c4 + 0] = kv.x; Ks[r][c4 + 1] = kv.y;
            Ks[r][c4 + 2] = kv.z; Ks[r][c4 + 3] = kv.w;
            *(float4*)&Vs[r][c4] = vv;
        }
        __syncthreads();

        // ---- S tile: 64x64, 4x4 per thread ----
        float acc[4][4];
#pragma unroll
        for (int i = 0; i < 4; ++i)
#pragma unroll
            for (int j = 0; j < 4; ++j) acc[i][j] = 0.f;
#pragma unroll
        for (int d = 0; d < D_; ++d) {
            float qv[4], kv[4];
#pragma unroll
            for (int i = 0; i < 4; ++i) qv[i] = Qs[ty * 4 + i][d];
#pragma unroll
            for (int j = 0; j < 4; ++j) kv[j] = Ks[tx * 4 + j][d];
#pragma unroll
            for (int i = 0; i < 4; ++i)
#pragma unroll
                for (int j = 0; j < 4; ++j) acc[i][j] += qv[i] * kv[j];
        }
#pragma unroll
        for (int i = 0; i < 4; ++i)
#pragma unroll
            for (int j = 0; j < 4; ++j) {
                int kj = j0 + tx * 4 + j;
                Ss[ty * 4 + i][tx * 4 + j] = (kj < S_) ? acc[i][j] : -1e30f;
            }
        __syncthreads();

        // ---- online softmax (one thread per q-row) ----
        if (tid < TQ) {
            int r = tid;
            float mx = m_i;
            for (int j = 0; j < TK; ++j) mx = fmaxf(mx, Ss[r][j]);
            float alpha = expf(m_i - mx);
            float sum = 0.f;
            for (int j = 0; j < TK; ++j) {
                float p = expf(Ss[r][j] - mx);
                Ss[r][j] = p;
                sum += p;
            }
            l_i = l_i * alpha + sum;
            m_i = mx;
            alpha_s[r] = alpha;
        }
        __syncthreads();

        // ---- PV: o = o*alpha + P @ V ----
        float alpha = alpha_s[rr];
#pragma unroll
        for (int i = 0; i < 8; ++i) o_acc[i] *= alpha;
        for (int j = 0; j < TK; ++j) {
            float p = Ss[rr][j];
            float4 v0 = *(const float4*)&Vs[j][dq * 8];
            float4 v1 = *(const float4*)&Vs[j][dq * 8 + 4];
            o_acc[0] += p * v0.x; o_acc[1] += p * v0.y;
            o_acc[2] += p * v0.z; o_acc[3] += p * v0.w;
            o_acc[4] += p * v1.x; o_acc[5] += p * v1.y;
            o_acc[6] += p * v1.z; o_acc[7] += p * v1.w;
        }
    }

    if (tid < TQ) l_s[tid] = l_i;
    __syncthreads();
    int gq = q0 + rr;
    if (gq < S_) {
        float inv = 1.0f / (l_s[rr] * 16.0f);   // /sqrt(E)=16 AFTER softmax
        float* obase = o + ((long)b * S_ + gq) * E_ + hh * D_ + dq * 8;
        float4 r0 = make_float4(o_acc[0] * inv, o_acc[1] * inv, o_acc[2] * inv, o_acc[3] * inv);
        float4 r1 = make_float4(o_acc[4] * inv, o_acc[5] * inv, o_acc[6] * inv, o_acc[7] * inv);
        *(float4*)obase = r0;
        *(float4*)(obase + 4) = r1;
    }
}

// --------------- Classifier: mean-pool -> Linear -> LN -> Linear ----------
__global__ void cls_kernel(const float* __restrict__ h, const float* __restrict__ Wc1,
                           const float* __restrict__ bc1, const float* __restrict__ lg,
                           const float* __restrict__ lb, const float* __restrict__ Wc2,
                           const float* __restrict__ bc2, float* __restrict__ out)
{
    int b = blockIdx.x;
    int e = threadIdx.x;
    __shared__ float p[256];
    __shared__ float red[256];
    __shared__ float lnv[256];

    float acc = 0.f;
    for (int s = 0; s < S_; ++s) acc += h[((long)b * S_ + s) * E_ + e];
    p[e] = acc * (1.0f / S_);
    __syncthreads();

    float c1 = bc1[e];
    for (int kk = 0; kk < E_; ++kk) c1 += p[kk] * Wc1[kk * E_ + e];

    red[e] = c1; __syncthreads();
    for (int st = 128; st; st >>= 1) { if (e < st) red[e] += red[e + st]; __syncthreads(); }
    float mean = red[0] * (1.0f / E_); __syncthreads();
    float d = c1 - mean;
    red[e] = d * d; __syncthreads();
    for (int st = 128; st; st >>= 1) { if (e < st) red[e] += red[e + st]; __syncthreads(); }
    float var = red[0] * (1.0f / E_);
    lnv[e] = d * rsqrtf(var + EPS_) * lg[e] + lb[e];
    __syncthreads();

    if (e < NC_) {
        float oacc = bc2[e];
        for (int kk = 0; kk < E_; ++kk) oacc += lnv[kk] * Wc2[kk * NC_ + e];
        out[b * NC_ + e] = oacc;
    }
}

extern "C" void kernel_launch(void* const* d_in, const int* in_sizes, int n_in,
                              void* d_out, int out_size, void* d_ws, size_t ws_size,
                              hipStream_t stream)
{
    const float* x      = (const float*)d_in[0];
    const float* W_emb  = (const float*)d_in[1];
    const float* b_emb  = (const float*)d_in[2];
    const float* g_emb  = (const float*)d_in[3];
    const float* be_emb = (const float*)d_in[4];
    const float* cls    = (const float*)d_in[5];
    const float* pos    = (const float*)d_in[6];
    const float* ln1_g  = (const float*)d_in[7];
    const float* ln1_b  = (const float*)d_in[8];
    const float* Wq     = (const float*)d_in[9];
    const float* bq     = (const float*)d_in[10];
    const float* Wk     = (const float*)d_in[11];
    const float* bk     = (const float*)d_in[12];
    const float* Wv     = (const float*)d_in[13];
    const float* bv     = (const float*)d_in[14];
    const float* Wo     = (const float*)d_in[15];
    const float* bo     = (const float*)d_in[16];
    const float* ln2_g  = (const float*)d_in[17];
    const float* ln2_b  = (const float*)d_in[18];
    const float* W1     = (const float*)d_in[19];
    const float* b1     = (const float*)d_in[20];
    const float* W2     = (const float*)d_in[21];
    const float* b2     = (const float*)d_in[22];
    const float* Wc1    = (const float*)d_in[23];
    const float* bc1    = (const float*)d_in[24];
    const float* lnc_g  = (const float*)d_in[25];
    const float* lnc_b  = (const float*)d_in[26];
    const float* Wc2    = (const float*)d_in[27];
    const float* bc2    = (const float*)d_in[28];
    float* out = (float*)d_out;

    float* ws = (float*)d_ws;
    float* h  = ws;                  // M_*E_
    float* y  = h  + (long)M_ * E_;  // M_*E_
    float* qb = y  + (long)M_ * E_;
    float* kb = qb + (long)M_ * E_;
    float* vb = kb + (long)M_ * E_;
    float* ob = vb + (long)M_ * E_;
    float* tb = ob + (long)M_ * E_;  // M_*XE_

    dim3 blk2(16, 16);
    dim3 gEE((E_ + TS - 1) / TS, (M_ + TS - 1) / TS);    // (8, 257)
    dim3 gEX((XE_ + TS - 1) / TS, (M_ + TS - 1) / TS);   // (32, 257)

    embed_kernel<<<M_, 256, 0, stream>>>(x, W_emb, b_emb, g_emb, be_emb, cls, h);

    for (int l = 0; l < L_; ++l) {
        // h += pos; y = LN1(h)
        ln_kernel<<<M_, 256, 0, stream>>>(h, pos, ln1_g + l * E_, ln1_b + l * E_, y);
        // Q, K, V
        gemm_kernel<<<gEE, blk2, 0, stream>>>(y, Wq + (long)l * E_ * E_, bq + l * E_, nullptr, qb, M_, E_, E_, 0);
        gemm_kernel<<<gEE, blk2, 0, stream>>>(y, Wk + (long)l * E_ * E_, bk + l * E_, nullptr, kb, M_, E_, E_, 0);
        gemm_kernel<<<gEE, blk2, 0, stream>>>(y, Wv + (long)l * E_ * E_, bv + l * E_, nullptr, vb, M_, E_, E_, 0);
        // attention (flash-style)
        flash_attn_kernel<<<B_ * H_ * NQT, 256, 0, stream>>>(qb, kb, vb, ob);
        // h = h + o@Wo + bo
        gemm_kernel<<<gEE, blk2, 0, stream>>>(ob, Wo + (long)l * E_ * E_, bo + l * E_, h, h, M_, E_, E_, 0);
        // y = LN2(h); t = GELU(y@W1+b1); h = h + t@W2+b2
        ln_kernel<<<M_, 256, 0, stream>>>(h, nullptr, ln2_g + l * E_, ln2_b + l * E_, y);
        gemm_kernel<<<gEX, blk2, 0, stream>>>(y, W1 + (long)l * E_ * XE_, b1 + l * XE_, nullptr, tb, M_, E_, XE_, 1);
        gemm_kernel<<<gEE, blk2, 0, stream>>>(tb, W2 + (long)l * XE_ * E_, b2 + l * E_, h, h, M_, XE_, E_, 0);
    }

    cls_kernel<<<B_, 256, 0, stream>>>(h, Wc1, bc1, lnc_g, lnc_b, Wc2, bc2, out);
}

// Round 3
// 884.840 us; speedup vs baseline: 8.8809x; 5.3638x over previous
//
#include <hip/hip_runtime.h>
#include <hip/hip_bf16.h>
#include <math.h>

// Problem constants
#define B_  8
#define N_  1024
#define C_  12
#define E_  256
#define H_  8
#define D_  32      // E/H
#define L_  4
#define XE_ 1024    // X*E
#define NC_ 5
#define S_  1025    // N+1
#define M_  8200    // B*S
#define EPS_ 1e-5f

typedef short bf16x8 __attribute__((ext_vector_type(8)));
typedef float f32x4 __attribute__((ext_vector_type(4)));
typedef __hip_bfloat16 bf16;

// ---------------- Embedding: x@W_emb+b -> LN -> GELU; cls row raw ----------
__global__ void embed_kernel(const float* __restrict__ x, const float* __restrict__ Wemb,
                             const float* __restrict__ bemb, const float* __restrict__ g,
                             const float* __restrict__ be, const float* __restrict__ cls,
                             float* __restrict__ h)
{
    int t = blockIdx.x;            // 0..M_-1
    int b = t / S_, s = t % S_;
    int e = threadIdx.x;           // 0..255
    __shared__ float xs[16];
    __shared__ float red[256];

    if (s == 0) {                  // cls token, raw copy (pos added per layer)
        h[(long)t * E_ + e] = cls[e];
        return;
    }
    int n = s - 1;
    if (e < C_) xs[e] = x[((long)b * N_ + n) * C_ + e];
    __syncthreads();

    float acc = bemb[e];
#pragma unroll
    for (int c = 0; c < C_; ++c) acc += xs[c] * Wemb[c * E_ + e];

    red[e] = acc; __syncthreads();
    for (int st = 128; st; st >>= 1) { if (e < st) red[e] += red[e + st]; __syncthreads(); }
    float mean = red[0] * (1.0f / E_); __syncthreads();
    float d = acc - mean;
    red[e] = d * d; __syncthreads();
    for (int st = 128; st; st >>= 1) { if (e < st) red[e] += red[e + st]; __syncthreads(); }
    float var = red[0] * (1.0f / E_);
    float ln = d * rsqrtf(var + EPS_) * g[e] + be[e];
    float gel = 0.5f * ln * (1.0f + erff(ln * 0.70710678118f));
    h[(long)t * E_ + e] = gel;
}

// --------------- (optional +pos into h) then LayerNorm -> y (bf16) ---------
__global__ void ln_kernel(float* __restrict__ h, const float* __restrict__ pos,
                          const float* __restrict__ g, const float* __restrict__ bb,
                          bf16* __restrict__ y)
{
    int t = blockIdx.x;            // token index
    int s = t % S_;
    int e = threadIdx.x;
    long idx = (long)t * E_ + e;
    __shared__ float red[256];

    float v = h[idx];
    if (pos) { v += pos[(long)s * E_ + e]; h[idx] = v; }

    red[e] = v; __syncthreads();
    for (int st = 128; st; st >>= 1) { if (e < st) red[e] += red[e + st]; __syncthreads(); }
    float mean = red[0] * (1.0f / E_); __syncthreads();
    float d = v - mean;
    red[e] = d * d; __syncthreads();
    for (int st = 128; st; st >>= 1) { if (e < st) red[e] += red[e + st]; __syncthreads(); }
    float var = red[0] * (1.0f / E_);
    y[idx] = __float2bfloat16(d * rsqrtf(var + EPS_) * g[e] + bb[e]);
}

// --------------- Weight packing: Wt[n][k] = bf16(W[k][n]) ------------------
__global__ void pack_wt(const float* __restrict__ W, bf16* __restrict__ Wt, int K, int N)
{
    int n = blockIdx.x;
    for (int kk = threadIdx.x; kk < K; kk += 256)
        Wt[(long)n * K + kk] = __float2bfloat16(W[(long)kk * N + n]);
}

// QKV fused pack: Wqkvt[l][768][256], bqkv[l][768]
__global__ void pack_qkv(const float* __restrict__ Wq, const float* __restrict__ Wk,
                         const float* __restrict__ Wv, const float* __restrict__ bq,
                         const float* __restrict__ bk, const float* __restrict__ bv,
                         bf16* __restrict__ Wt, float* __restrict__ bqkv)
{
    int n = blockIdx.x % 768, l = blockIdx.x / 768;
    int kk = threadIdx.x;
    const float* src; const float* bsrc; int col;
    if (n < 256)      { src = Wq + (long)l * 65536; bsrc = bq + l * 256; col = n; }
    else if (n < 512) { src = Wk + (long)l * 65536; bsrc = bk + l * 256; col = n - 256; }
    else              { src = Wv + (long)l * 65536; bsrc = bv + l * 256; col = n - 512; }
    Wt[((long)l * 768 + n) * 256 + kk] = __float2bfloat16(src[(long)kk * 256 + col]);
    if (kk == 0) bqkv[l * 768 + n] = bsrc[col];
}

// --------------- bf16 MFMA GEMM: out = act(A@Wt^T + bias) [+res] ----------
// A: [M][K] bf16 row-major; Wt: [N][K] bf16 (pre-transposed). 64x64 tile.
__global__ __launch_bounds__(256) void gemm_bf16(
    const bf16* __restrict__ A, const bf16* __restrict__ Wt,
    const float* __restrict__ bias, const float* __restrict__ res,
    float* __restrict__ outF, bf16* __restrict__ outB,
    int M, int K, int N, int act)
{
    __shared__ bf16 As[64 * 72];   // row stride 72 bf16 = 144B (16B mult, pad kills read conflicts)
    __shared__ bf16 Bs[64 * 72];
    int tid = threadIdx.x;
    int wave = tid >> 6, lane = tid & 63;
    int quad = lane >> 4, l16 = lane & 15;
    int row0 = blockIdx.y * 64;
    int col0 = blockIdx.x * 64;

    f32x4 acc[4] = {{0.f,0.f,0.f,0.f},{0.f,0.f,0.f,0.f},{0.f,0.f,0.f,0.f},{0.f,0.f,0.f,0.f}};
    uint4 z4 = make_uint4(0,0,0,0);

    int nk = K >> 6;
    for (int kt = 0; kt < nk; ++kt) {
        int k0 = kt << 6;
        __syncthreads();
        for (int c = tid; c < 512; c += 256) {     // A tile: 64 rows x 8 chunks
            int r = c >> 3, off = (c & 7) * 8;
            uint4 val = z4;
            int gr = row0 + r;
            if (gr < M) val = *(const uint4*)(A + (long)gr * K + k0 + off);
            *(uint4*)&As[r * 72 + off] = val;
        }
        for (int c = tid; c < 512; c += 256) {     // Wt tile (straight copy)
            int r = c >> 3, off = (c & 7) * 8;
            *(uint4*)&Bs[r * 72 + off] = *(const uint4*)(Wt + (long)(col0 + r) * K + k0 + off);
        }
        __syncthreads();
#pragma unroll
        for (int ks = 0; ks < 64; ks += 32) {
            bf16x8 af = *(const bf16x8*)&As[(wave * 16 + l16) * 72 + ks + quad * 8];
#pragma unroll
            for (int nt = 0; nt < 4; ++nt) {
                bf16x8 bf = *(const bf16x8*)&Bs[(nt * 16 + l16) * 72 + ks + quad * 8];
                acc[nt] = __builtin_amdgcn_mfma_f32_16x16x32_bf16(af, bf, acc[nt], 0, 0, 0);
            }
        }
    }
    // epilogue: C/D layout col=lane&15, row=quad*4+reg
#pragma unroll
    for (int nt = 0; nt < 4; ++nt) {
        int col = col0 + nt * 16 + l16;
#pragma unroll
        for (int r = 0; r < 4; ++r) {
            int m = row0 + wave * 16 + quad * 4 + r;
            if (m >= M) continue;
            float v = acc[nt][r] + bias[col];
            if (act == 1) v = 0.5f * v * (1.0f + erff(v * 0.70710678118f));
            if (res)  v += res[(long)m * N + col];
            if (outF) outF[(long)m * N + col] = v;
            if (outB) outB[(long)m * N + col] = __float2bfloat16(v);
        }
    }
}

// --------------- MFMA flash attention -------------------------------------
// qkv: [M][768] bf16 (q|k|v each 256 = 8 heads x 32). ob: [M][256] bf16.
// softmax over keys then /16. No max-subtraction (scores O(1-10); clamp 60).
#define NQT 17
__global__ __launch_bounds__(256) void attn_mfma_kernel(
    const bf16* __restrict__ qkv, bf16* __restrict__ ob)
{
    __shared__ bf16 Ks[64 * 40];       // [key][d] stride 40 (80B, 16B mult)
    __shared__ bf16 Vt[32 * 72];       // [d][key] stride 72 (144B)
    __shared__ bf16 Pa[4 * 16 * 72];   // per-wave P_t [q][key] stride 72

    int tid = threadIdx.x;
    int wave = tid >> 6, lane = tid & 63;
    int quad = lane >> 4, l16 = lane & 15;
    int bh = blockIdx.x / NQT, qt = blockIdx.x % NQT;
    int b = bh / H_, hh = bh % H_;
    int q0 = qt * 64;
    long bS = (long)b * S_;
    int qoff = hh * 32, koff = 256 + hh * 32;
    bf16* Pw = Pa + wave * 16 * 72;
    uint4 z4 = make_uint4(0,0,0,0);

    // Q-frag, register-resident for whole kernel: A[m=q(l16)][k=d(quad*8+j)]
    bf16x8 aq = {0,0,0,0,0,0,0,0};
    {
        int gq = q0 + wave * 16 + l16;
        if (gq < S_) aq = *(const bf16x8*)(qkv + (bS + gq) * 768 + qoff + quad * 8);
    }

    f32x4 o0 = {0.f,0.f,0.f,0.f}, o1 = {0.f,0.f,0.f,0.f};
    float lsum[4] = {0.f, 0.f, 0.f, 0.f};
    f32x4 zf = {0.f,0.f,0.f,0.f};

    for (int kt = 0; kt < NQT; ++kt) {
        int j0 = kt * 64;
        __syncthreads();
        {   // stage K (straight) and V (transposed): 256 threads = 64 keys x 4 dgroups
            int key = tid >> 2, dg = tid & 3;
            int gk = j0 + key;
            uint4 kv = z4, vv = z4;
            if (gk < S_) {
                const bf16* kp = qkv + (bS + gk) * 768 + koff + dg * 8;
                kv = *(const uint4*)kp;
                vv = *(const uint4*)(kp + 256);   // v is 256 past k
            }
            *(uint4*)&Ks[key * 40 + dg * 8] = kv;
            const bf16* vs = (const bf16*)&vv;
#pragma unroll
            for (int i = 0; i < 8; ++i) Vt[(dg * 8 + i) * 72 + key] = vs[i];
        }
        __syncthreads();

        // scores: 4 mfma -> S[16q x 64k] per wave (C: col=key(l16), row=q(quad*4+r))
        f32x4 sc[4];
#pragma unroll
        for (int t4 = 0; t4 < 4; ++t4) {
            bf16x8 bk = *(const bf16x8*)&Ks[(t4 * 16 + l16) * 40 + quad * 8];
            sc[t4] = __builtin_amdgcn_mfma_f32_16x16x32_bf16(aq, bk, zf, 0, 0, 0);
        }
        // exp (shift-free softmax), accumulate l, write P_t to own-wave LDS
#pragma unroll
        for (int t4 = 0; t4 < 4; ++t4) {
            bool valid = (j0 + t4 * 16 + l16) < S_;
#pragma unroll
            for (int r = 0; r < 4; ++r) {
                float p = valid ? __expf(fminf(sc[t4][r], 60.f)) : 0.f;
                lsum[r] += p;
                Pw[(quad * 4 + r) * 72 + t4 * 16 + l16] = __float2bfloat16(p);
            }
        }
        // PV: A=P[q][key], B=V[key][d] via Vt; accumulate O (C layout)
#pragma unroll
        for (int ks2 = 0; ks2 < 64; ks2 += 32) {
            bf16x8 ap = *(const bf16x8*)&Pw[l16 * 72 + ks2 + quad * 8];
            bf16x8 bv0 = *(const bf16x8*)&Vt[(0 * 16 + l16) * 72 + ks2 + quad * 8];
            o0 = __builtin_amdgcn_mfma_f32_16x16x32_bf16(ap, bv0, o0, 0, 0, 0);
            bf16x8 bv1 = *(const bf16x8*)&Vt[(1 * 16 + l16) * 72 + ks2 + quad * 8];
            o1 = __builtin_amdgcn_mfma_f32_16x16x32_bf16(ap, bv1, o1, 0, 0, 0);
        }
    }

    // normalize (1/(l*16), /sqrt(E) after softmax) and store
#pragma unroll
    for (int r = 0; r < 4; ++r) {
        float t = lsum[r];
        t += __shfl_xor(t, 1); t += __shfl_xor(t, 2);
        t += __shfl_xor(t, 4); t += __shfl_xor(t, 8);
        float inv = 1.0f / (t * 16.0f);
        int gq = q0 + wave * 16 + quad * 4 + r;
        if (gq < S_) {
            long base = (bS + gq) * 256 + hh * 32;
            ob[base + l16]      = __float2bfloat16(o0[r] * inv);
            ob[base + 16 + l16] = __float2bfloat16(o1[r] * inv);
        }
    }
}

// --------------- Classifier: mean-pool -> Linear -> LN -> Linear ----------
__global__ void cls_kernel(const float* __restrict__ h, const float* __restrict__ Wc1,
                           const float* __restrict__ bc1, const float* __restrict__ lg,
                           const float* __restrict__ lb, const float* __restrict__ Wc2,
                           const float* __restrict__ bc2, float* __restrict__ out)
{
    int b = blockIdx.x;
    int e = threadIdx.x;
    __shared__ float p[256];
    __shared__ float red[256];
    __shared__ float lnv[256];

    float acc = 0.f;
    for (int s = 0; s < S_; ++s) acc += h[((long)b * S_ + s) * E_ + e];
    p[e] = acc * (1.0f / S_);
    __syncthreads();

    float c1 = bc1[e];
    for (int kk = 0; kk < E_; ++kk) c1 += p[kk] * Wc1[kk * E_ + e];

    red[e] = c1; __syncthreads();
    for (int st = 128; st; st >>= 1) { if (e < st) red[e] += red[e + st]; __syncthreads(); }
    float mean = red[0] * (1.0f / E_); __syncthreads();
    float d = c1 - mean;
    red[e] = d * d; __syncthreads();
    for (int st = 128; st; st >>= 1) { if (e < st) red[e] += red[e + st]; __syncthreads(); }
    float var = red[0] * (1.0f / E_);
    lnv[e] = d * rsqrtf(var + EPS_) * lg[e] + lb[e];
    __syncthreads();

    if (e < NC_) {
        float oacc = bc2[e];
        for (int kk = 0; kk < E_; ++kk) oacc += lnv[kk] * Wc2[kk * NC_ + e];
        out[b * NC_ + e] = oacc;
    }
}

extern "C" void kernel_launch(void* const* d_in, const int* in_sizes, int n_in,
                              void* d_out, int out_size, void* d_ws, size_t ws_size,
                              hipStream_t stream)
{
    const float* x      = (const float*)d_in[0];
    const float* W_emb  = (const float*)d_in[1];
    const float* b_emb  = (const float*)d_in[2];
    const float* g_emb  = (const float*)d_in[3];
    const float* be_emb = (const float*)d_in[4];
    const float* cls    = (const float*)d_in[5];
    const float* pos    = (const float*)d_in[6];
    const float* ln1_g  = (const float*)d_in[7];
    const float* ln1_b  = (const float*)d_in[8];
    const float* Wq     = (const float*)d_in[9];
    const float* bq     = (const float*)d_in[10];
    const float* Wk     = (const float*)d_in[11];
    const float* bk     = (const float*)d_in[12];
    const float* Wv     = (const float*)d_in[13];
    const float* bv     = (const float*)d_in[14];
    const float* Wo     = (const float*)d_in[15];
    const float* bo     = (const float*)d_in[16];
    const float* ln2_g  = (const float*)d_in[17];
    const float* ln2_b  = (const float*)d_in[18];
    const float* W1     = (const float*)d_in[19];
    const float* b1     = (const float*)d_in[20];
    const float* W2     = (const float*)d_in[21];
    const float* b2     = (const float*)d_in[22];
    const float* Wc1    = (const float*)d_in[23];
    const float* bc1    = (const float*)d_in[24];
    const float* lnc_g  = (const float*)d_in[25];
    const float* lnc_b  = (const float*)d_in[26];
    const float* Wc2    = (const float*)d_in[27];
    const float* bc2    = (const float*)d_in[28];
    float* out = (float*)d_out;

    char* p = (char*)d_ws;
    float* h   = (float*)p;  p += (long)M_ * 256 * 4;
    bf16* y    = (bf16*)p;   p += (long)M_ * 256 * 2;
    bf16* qkv  = (bf16*)p;   p += (long)M_ * 768 * 2;
    bf16* obuf = (bf16*)p;   p += (long)M_ * 256 * 2;
    bf16* tb   = (bf16*)p;   p += (long)M_ * 1024 * 2;
    bf16* Wqkvt = (bf16*)p;  p += (long)L_ * 768 * 256 * 2;
    bf16* Wot   = (bf16*)p;  p += (long)L_ * 256 * 256 * 2;
    bf16* W1t   = (bf16*)p;  p += (long)L_ * 1024 * 256 * 2;
    bf16* W2t   = (bf16*)p;  p += (long)L_ * 256 * 1024 * 2;
    float* bqkv = (float*)p; p += (long)L_ * 768 * 4;

    // ---- weight packing (repeated every call; inputs restored each call) ----
    pack_qkv<<<L_ * 768, 256, 0, stream>>>(Wq, Wk, Wv, bq, bk, bv, Wqkvt, bqkv);
    for (int l = 0; l < L_; ++l) {
        pack_wt<<<256,  256, 0, stream>>>(Wo + (long)l * 65536,  Wot + (long)l * 65536,  256, 256);
        pack_wt<<<1024, 256, 0, stream>>>(W1 + (long)l * 262144, W1t + (long)l * 262144, 256, 1024);
        pack_wt<<<256,  256, 0, stream>>>(W2 + (long)l * 262144, W2t + (long)l * 262144, 1024, 256);
    }

    embed_kernel<<<M_, 256, 0, stream>>>(x, W_emb, b_emb, g_emb, be_emb, cls, h);

    dim3 gQKV(12, 129), gEE(4, 129), gMLP1(16, 129);
    for (int l = 0; l < L_; ++l) {
        ln_kernel<<<M_, 256, 0, stream>>>(h, pos, ln1_g + l * E_, ln1_b + l * E_, y);
        gemm_bf16<<<gQKV, 256, 0, stream>>>(y, Wqkvt + (long)l * 768 * 256, bqkv + l * 768,
                                            nullptr, nullptr, qkv, M_, 256, 768, 0);
        attn_mfma_kernel<<<B_ * H_ * NQT, 256, 0, stream>>>(qkv, obuf);
        gemm_bf16<<<gEE, 256, 0, stream>>>(obuf, Wot + (long)l * 65536, bo + l * E_,
                                           h, h, nullptr, M_, 256, 256, 0);
        ln_kernel<<<M_, 256, 0, stream>>>(h, nullptr, ln2_g + l * E_, ln2_b + l * E_, y);
        gemm_bf16<<<gMLP1, 256, 0, stream>>>(y, W1t + (long)l * 262144, b1 + l * XE_,
                                             nullptr, nullptr, tb, M_, 256, 1024, 1);
        gemm_bf16<<<gEE, 256, 0, stream>>>(tb, W2t + (long)l * 262144, b2 + l * E_,
                                           h, h, nullptr, M_, 1024, 256, 0);
    }

    cls_kernel<<<B_, 256, 0, stream>>>(h, Wc1, bc1, lnc_g, lnc_b, Wc2, bc2, out);
}

// Round 4
// 816.180 us; speedup vs baseline: 9.6279x; 1.0841x over previous
//
#include <hip/hip_runtime.h>
#include <hip/hip_bf16.h>
#include <math.h>

// Problem constants
#define B_  8
#define N_  1024
#define C_  12
#define E_  256
#define H_  8
#define D_  32      // E/H
#define L_  4
#define XE_ 1024    // X*E
#define NC_ 5
#define S_  1025    // N+1
#define M_  8200    // B*S
#define EPS_ 1e-5f

typedef short bf16x8 __attribute__((ext_vector_type(8)));
typedef float f32x4 __attribute__((ext_vector_type(4)));
typedef __hip_bfloat16 bf16;

// ---------------- Embedding (wave per token): x@W+b -> LN -> GELU ----------
__global__ __launch_bounds__(256) void embed4_kernel(
    const float* __restrict__ x, const float* __restrict__ Wemb,
    const float* __restrict__ bemb, const float* __restrict__ g,
    const float* __restrict__ be, const float* __restrict__ cls,
    float* __restrict__ h)
{
    int wave = threadIdx.x >> 6, lane = threadIdx.x & 63;
    int t = blockIdx.x * 4 + wave;          // M_ = 4*2050 exactly
    int b = t / S_, s = t % S_;
    long base = (long)t * E_ + lane * 4;

    if (s == 0) {                            // cls token raw
        *(float4*)(h + base) = *(const float4*)(cls + lane * 4);
        return;
    }
    const float* xr = x + ((long)b * N_ + (s - 1)) * C_;
    float xv[C_];
#pragma unroll
    for (int c = 0; c < C_; ++c) xv[c] = xr[c];   // wave-broadcast loads

    float4 acc = *(const float4*)(bemb + lane * 4);
#pragma unroll
    for (int c = 0; c < C_; ++c) {
        float4 w = *(const float4*)(Wemb + c * E_ + lane * 4);
        acc.x += xv[c] * w.x; acc.y += xv[c] * w.y;
        acc.z += xv[c] * w.z; acc.w += xv[c] * w.w;
    }
    float sum = acc.x + acc.y + acc.z + acc.w;
    float sq  = acc.x*acc.x + acc.y*acc.y + acc.z*acc.z + acc.w*acc.w;
#pragma unroll
    for (int off = 1; off < 64; off <<= 1) {
        sum += __shfl_xor(sum, off);
        sq  += __shfl_xor(sq,  off);
    }
    float mean = sum * (1.0f / E_);
    float var  = sq * (1.0f / E_) - mean * mean;
    float rstd = rsqrtf(var + EPS_);
    float4 gg = *(const float4*)(g + lane * 4);
    float4 bb = *(const float4*)(be + lane * 4);
    float4 o;
    float v;
    v = (acc.x - mean) * rstd * gg.x + bb.x; o.x = 0.5f * v * (1.0f + erff(v * 0.70710678118f));
    v = (acc.y - mean) * rstd * gg.y + bb.y; o.y = 0.5f * v * (1.0f + erff(v * 0.70710678118f));
    v = (acc.z - mean) * rstd * gg.z + bb.z; o.z = 0.5f * v * (1.0f + erff(v * 0.70710678118f));
    v = (acc.w - mean) * rstd * gg.w + bb.w; o.w = 0.5f * v * (1.0f + erff(v * 0.70710678118f));
    *(float4*)(h + base) = o;
}

// ------------- LN (wave per token): optional h+=pos, y=bf16(LN(h)) ---------
__global__ __launch_bounds__(256) void ln4_kernel(
    float* __restrict__ h, const float* __restrict__ pos,
    const float* __restrict__ g, const float* __restrict__ bb,
    bf16* __restrict__ y)
{
    int wave = threadIdx.x >> 6, lane = threadIdx.x & 63;
    int t = blockIdx.x * 4 + wave;
    int s = t % S_;
    long base = (long)t * E_ + lane * 4;

    float4 v = *(const float4*)(h + base);
    if (pos) {
        float4 pv = *(const float4*)(pos + (long)s * E_ + lane * 4);
        v.x += pv.x; v.y += pv.y; v.z += pv.z; v.w += pv.w;
        *(float4*)(h + base) = v;
    }
    float sum = v.x + v.y + v.z + v.w;
    float sq  = v.x*v.x + v.y*v.y + v.z*v.z + v.w*v.w;
#pragma unroll
    for (int off = 1; off < 64; off <<= 1) {
        sum += __shfl_xor(sum, off);
        sq  += __shfl_xor(sq,  off);
    }
    float mean = sum * (1.0f / E_);
    float var  = sq * (1.0f / E_) - mean * mean;
    float rstd = rsqrtf(var + EPS_);
    float4 gg = *(const float4*)(g + lane * 4);
    float4 b4 = *(const float4*)(bb + lane * 4);
    bf16 o[4];
    o[0] = __float2bfloat16((v.x - mean) * rstd * gg.x + b4.x);
    o[1] = __float2bfloat16((v.y - mean) * rstd * gg.y + b4.y);
    o[2] = __float2bfloat16((v.z - mean) * rstd * gg.z + b4.z);
    o[3] = __float2bfloat16((v.w - mean) * rstd * gg.w + b4.w);
    *(uint2*)(y + base) = *(uint2*)o;
}

// ---------- Pack (LDS 32x32 transpose): Wt[l][n][k] = bf16(W[l][k][n]) -----
__global__ void pack_wt_t(const float* __restrict__ W, bf16* __restrict__ Wt,
                          int K, int N)
{
    __shared__ float tile[32][33];
    int l = blockIdx.z;
    int n0 = blockIdx.x * 32, k0 = blockIdx.y * 32;
    int tx = threadIdx.x & 31, ty = threadIdx.x >> 5;   // 32x8
    const float* Ws = W + (long)l * K * N;
    bf16* Wts = Wt + (long)l * K * N;
#pragma unroll
    for (int i = 0; i < 4; ++i)
        tile[ty + i * 8][tx] = Ws[(long)(k0 + ty + i * 8) * N + n0 + tx];
    __syncthreads();
#pragma unroll
    for (int i = 0; i < 4; ++i)
        Wts[(long)(n0 + ty + i * 8) * K + k0 + tx] = __float2bfloat16(tile[tx][ty + i * 8]);
}

// QKV fused pack: Wqkvt[l][768][256] (q|k|v), bqkv[l][768]
__global__ void pack_qkv_t(const float* __restrict__ Wq, const float* __restrict__ Wk,
                           const float* __restrict__ Wv, const float* __restrict__ bq,
                           const float* __restrict__ bk, const float* __restrict__ bv,
                           bf16* __restrict__ Wt, float* __restrict__ bqkv)
{
    __shared__ float tile[32][33];
    int l = blockIdx.z;
    int n0 = blockIdx.x * 32, k0 = blockIdx.y * 32;
    int tx = threadIdx.x & 31, ty = threadIdx.x >> 5;
    const float* src; const float* bsrc; int c0;
    if (n0 < 256)      { src = Wq + (long)l * 65536; bsrc = bq + l * 256; c0 = n0; }
    else if (n0 < 512) { src = Wk + (long)l * 65536; bsrc = bk + l * 256; c0 = n0 - 256; }
    else               { src = Wv + (long)l * 65536; bsrc = bv + l * 256; c0 = n0 - 512; }
#pragma unroll
    for (int i = 0; i < 4; ++i)
        tile[ty + i * 8][tx] = src[(long)(k0 + ty + i * 8) * 256 + c0 + tx];
    __syncthreads();
    bf16* Wts = Wt + (long)l * 768 * 256;
#pragma unroll
    for (int i = 0; i < 4; ++i)
        Wts[(long)(n0 + ty + i * 8) * 256 + k0 + tx] = __float2bfloat16(tile[tx][ty + i * 8]);
    if (blockIdx.y == 0 && ty == 0)
        bqkv[l * 768 + n0 + tx] = bsrc[c0 + tx];
}

// ------- bf16 MFMA GEMM 64x64 tile: out = act(A@Wt^T + bias) [+res] -------
__global__ __launch_bounds__(256) void gemm_bf16(
    const bf16* __restrict__ A, const bf16* __restrict__ Wt,
    const float* __restrict__ bias, const float* __restrict__ res,
    float* __restrict__ outF, bf16* __restrict__ outB,
    int M, int K, int N, int act)
{
    __shared__ bf16 As[64 * 72];
    __shared__ bf16 Bs[64 * 72];
    int tid = threadIdx.x;
    int wave = tid >> 6, lane = tid & 63;
    int quad = lane >> 4, l16 = lane & 15;
    int row0 = blockIdx.y * 64;
    int col0 = blockIdx.x * 64;

    f32x4 acc[4] = {{0.f,0.f,0.f,0.f},{0.f,0.f,0.f,0.f},{0.f,0.f,0.f,0.f},{0.f,0.f,0.f,0.f}};
    uint4 z4 = make_uint4(0,0,0,0);

    int nk = K >> 6;
    for (int kt = 0; kt < nk; ++kt) {
        int k0 = kt << 6;
        __syncthreads();
        for (int c = tid; c < 512; c += 256) {
            int r = c >> 3, off = (c & 7) * 8;
            uint4 val = z4;
            int gr = row0 + r;
            if (gr < M) val = *(const uint4*)(A + (long)gr * K + k0 + off);
            *(uint4*)&As[r * 72 + off] = val;
        }
        for (int c = tid; c < 512; c += 256) {
            int r = c >> 3, off = (c & 7) * 8;
            *(uint4*)&Bs[r * 72 + off] = *(const uint4*)(Wt + (long)(col0 + r) * K + k0 + off);
        }
        __syncthreads();
#pragma unroll
        for (int ks = 0; ks < 64; ks += 32) {
            bf16x8 af = *(const bf16x8*)&As[(wave * 16 + l16) * 72 + ks + quad * 8];
#pragma unroll
            for (int nt = 0; nt < 4; ++nt) {
                bf16x8 bf = *(const bf16x8*)&Bs[(nt * 16 + l16) * 72 + ks + quad * 8];
                acc[nt] = __builtin_amdgcn_mfma_f32_16x16x32_bf16(af, bf, acc[nt], 0, 0, 0);
            }
        }
    }
#pragma unroll
    for (int nt = 0; nt < 4; ++nt) {
        int col = col0 + nt * 16 + l16;
#pragma unroll
        for (int r = 0; r < 4; ++r) {
            int m = row0 + wave * 16 + quad * 4 + r;
            if (m >= M) continue;
            float v = acc[nt][r] + bias[col];
            if (act == 1) v = 0.5f * v * (1.0f + erff(v * 0.70710678118f));
            if (res)  v += res[(long)m * N + col];
            if (outF) outF[(long)m * N + col] = v;
            if (outB) outB[(long)m * N + col] = __float2bfloat16(v);
        }
    }
}

// ------- bf16 MFMA GEMM 128x128 tile (N must be multiple of 128) ----------
__global__ __launch_bounds__(256) void gemm_bf16_128(
    const bf16* __restrict__ A, const bf16* __restrict__ Wt,
    const float* __restrict__ bias,
    float* __restrict__ outF, bf16* __restrict__ outB,
    int M, int K, int N, int act)
{
    __shared__ bf16 As[128 * 72];
    __shared__ bf16 Bs[128 * 72];
    int tid = threadIdx.x;
    int wave = tid >> 6, lane = tid & 63;
    int quad = lane >> 4, l16 = lane & 15;
    int wr = (wave >> 1) * 64, wc = (wave & 1) * 64;
    int row0 = blockIdx.y * 128;
    int col0 = blockIdx.x * 128;

    f32x4 acc[4][4];
#pragma unroll
    for (int i = 0; i < 4; ++i)
#pragma unroll
        for (int j = 0; j < 4; ++j) acc[i][j] = (f32x4){0.f,0.f,0.f,0.f};
    uint4 z4 = make_uint4(0,0,0,0);

    int nk = K >> 6;
    for (int kt = 0; kt < nk; ++kt) {
        int k0 = kt << 6;
        __syncthreads();
#pragma unroll
        for (int c = tid; c < 1024; c += 256) {
            int r = c >> 3, off = (c & 7) * 8;
            uint4 val = z4;
            int gr = row0 + r;
            if (gr < M) val = *(const uint4*)(A + (long)gr * K + k0 + off);
            *(uint4*)&As[r * 72 + off] = val;
        }
#pragma unroll
        for (int c = tid; c < 1024; c += 256) {
            int r = c >> 3, off = (c & 7) * 8;
            *(uint4*)&Bs[r * 72 + off] = *(const uint4*)(Wt + (long)(col0 + r) * K + k0 + off);
        }
        __syncthreads();
#pragma unroll
        for (int ks = 0; ks < 64; ks += 32) {
            bf16x8 af[4], bfr[4];
#pragma unroll
            for (int i = 0; i < 4; ++i)
                af[i] = *(const bf16x8*)&As[(wr + i * 16 + l16) * 72 + ks + quad * 8];
#pragma unroll
            for (int j = 0; j < 4; ++j)
                bfr[j] = *(const bf16x8*)&Bs[(wc + j * 16 + l16) * 72 + ks + quad * 8];
#pragma unroll
            for (int i = 0; i < 4; ++i)
#pragma unroll
                for (int j = 0; j < 4; ++j)
                    acc[i][j] = __builtin_amdgcn_mfma_f32_16x16x32_bf16(af[i], bfr[j], acc[i][j], 0, 0, 0);
        }
    }
#pragma unroll
    for (int i = 0; i < 4; ++i) {
#pragma unroll
        for (int j = 0; j < 4; ++j) {
            int col = col0 + wc + j * 16 + l16;
#pragma unroll
            for (int r = 0; r < 4; ++r) {
                int m = row0 + wr + i * 16 + quad * 4 + r;
                if (m >= M) continue;
                float v = acc[i][j][r] + bias[col];
                if (act == 1) v = 0.5f * v * (1.0f + erff(v * 0.70710678118f));
                if (outF) outF[(long)m * N + col] = v;
                if (outB) outB[(long)m * N + col] = __float2bfloat16(v);
            }
        }
    }
}

// --------------- MFMA flash attention (unchanged from R3) ------------------
#define NQT 17
__global__ __launch_bounds__(256) void attn_mfma_kernel(
    const bf16* __restrict__ qkv, bf16* __restrict__ ob)
{
    __shared__ bf16 Ks[64 * 40];
    __shared__ bf16 Vt[32 * 72];
    __shared__ bf16 Pa[4 * 16 * 72];

    int tid = threadIdx.x;
    int wave = tid >> 6, lane = tid & 63;
    int quad = lane >> 4, l16 = lane & 15;
    int bh = blockIdx.x / NQT, qt = blockIdx.x % NQT;
    int b = bh / H_, hh = bh % H_;
    int q0 = qt * 64;
    long bS = (long)b * S_;
    int qoff = hh * 32, koff = 256 + hh * 32;
    bf16* Pw = Pa + wave * 16 * 72;
    uint4 z4 = make_uint4(0,0,0,0);

    bf16x8 aq = {0,0,0,0,0,0,0,0};
    {
        int gq = q0 + wave * 16 + l16;
        if (gq < S_) aq = *(const bf16x8*)(qkv + (bS + gq) * 768 + qoff + quad * 8);
    }

    f32x4 o0 = {0.f,0.f,0.f,0.f}, o1 = {0.f,0.f,0.f,0.f};
    float lsum[4] = {0.f, 0.f, 0.f, 0.f};
    f32x4 zf = {0.f,0.f,0.f,0.f};

    for (int kt = 0; kt < NQT; ++kt) {
        int j0 = kt * 64;
        __syncthreads();
        {
            int key = tid >> 2, dg = tid & 3;
            int gk = j0 + key;
            uint4 kv = z4, vv = z4;
            if (gk < S_) {
                const bf16* kp = qkv + (bS + gk) * 768 + koff + dg * 8;
                kv = *(const uint4*)kp;
                vv = *(const uint4*)(kp + 256);
            }
            *(uint4*)&Ks[key * 40 + dg * 8] = kv;
            const bf16* vs = (const bf16*)&vv;
#pragma unroll
            for (int i = 0; i < 8; ++i) Vt[(dg * 8 + i) * 72 + key] = vs[i];
        }
        __syncthreads();

        f32x4 sc[4];
#pragma unroll
        for (int t4 = 0; t4 < 4; ++t4) {
            bf16x8 bk = *(const bf16x8*)&Ks[(t4 * 16 + l16) * 40 + quad * 8];
            sc[t4] = __builtin_amdgcn_mfma_f32_16x16x32_bf16(aq, bk, zf, 0, 0, 0);
        }
#pragma unroll
        for (int t4 = 0; t4 < 4; ++t4) {
            bool valid = (j0 + t4 * 16 + l16) < S_;
#pragma unroll
            for (int r = 0; r < 4; ++r) {
                float p = valid ? __expf(fminf(sc[t4][r], 60.f)) : 0.f;
                lsum[r] += p;
                Pw[(quad * 4 + r) * 72 + t4 * 16 + l16] = __float2bfloat16(p);
            }
        }
#pragma unroll
        for (int ks2 = 0; ks2 < 64; ks2 += 32) {
            bf16x8 ap = *(const bf16x8*)&Pw[l16 * 72 + ks2 + quad * 8];
            bf16x8 bv0 = *(const bf16x8*)&Vt[(0 * 16 + l16) * 72 + ks2 + quad * 8];
            o0 = __builtin_amdgcn_mfma_f32_16x16x32_bf16(ap, bv0, o0, 0, 0, 0);
            bf16x8 bv1 = *(const bf16x8*)&Vt[(1 * 16 + l16) * 72 + ks2 + quad * 8];
            o1 = __builtin_amdgcn_mfma_f32_16x16x32_bf16(ap, bv1, o1, 0, 0, 0);
        }
    }

#pragma unroll
    for (int r = 0; r < 4; ++r) {
        float t = lsum[r];
        t += __shfl_xor(t, 1); t += __shfl_xor(t, 2);
        t += __shfl_xor(t, 4); t += __shfl_xor(t, 8);
        float inv = 1.0f / (t * 16.0f);
        int gq = q0 + wave * 16 + quad * 4 + r;
        if (gq < S_) {
            long base = (bS + gq) * 256 + hh * 32;
            ob[base + l16]      = __float2bfloat16(o0[r] * inv);
            ob[base + 16 + l16] = __float2bfloat16(o1[r] * inv);
        }
    }
}

// --------------- Pool: partial[b][sc][e] = sum over 65-row chunk -----------
__global__ __launch_bounds__(256) void pool_kernel(const float* __restrict__ h,
                                                   float* __restrict__ partial)
{
    int b = blockIdx.x >> 4, sc = blockIdx.x & 15;
    int e = threadIdx.x;
    int s0 = sc * 65, s1 = min(S_, s0 + 65);
    float acc = 0.f;
    for (int s = s0; s < s1; ++s) acc += h[((long)b * S_ + s) * E_ + e];
    partial[((long)b * 16 + sc) * E_ + e] = acc;
}

// --------------- Classifier final: Linear -> LN -> Linear -----------------
__global__ __launch_bounds__(256) void cls_final(
    const float* __restrict__ partial, const float* __restrict__ Wc1,
    const float* __restrict__ bc1, const float* __restrict__ lg,
    const float* __restrict__ lb, const float* __restrict__ Wc2,
    const float* __restrict__ bc2, float* __restrict__ out)
{
    int b = blockIdx.x;
    int e = threadIdx.x;
    __shared__ float p[256];
    __shared__ float red[256];
    __shared__ float lnv[256];

    float acc = 0.f;
#pragma unroll
    for (int sc = 0; sc < 16; ++sc) acc += partial[((long)b * 16 + sc) * E_ + e];
    p[e] = acc * (1.0f / S_);
    __syncthreads();

    float c1 = bc1[e];
    for (int kk = 0; kk < E_; ++kk) c1 += p[kk] * Wc1[kk * E_ + e];

    red[e] = c1; __syncthreads();
    for (int st = 128; st; st >>= 1) { if (e < st) red[e] += red[e + st]; __syncthreads(); }
    float mean = red[0] * (1.0f / E_); __syncthreads();
    float d = c1 - mean;
    red[e] = d * d; __syncthreads();
    for (int st = 128; st; st >>= 1) { if (e < st) red[e] += red[e + st]; __syncthreads(); }
    float var = red[0] * (1.0f / E_);
    lnv[e] = d * rsqrtf(var + EPS_) * lg[e] + lb[e];
    __syncthreads();

    if (e < NC_) {
        float oacc = bc2[e];
        for (int kk = 0; kk < E_; ++kk) oacc += lnv[kk] * Wc2[kk * NC_ + e];
        out[b * NC_ + e] = oacc;
    }
}

extern "C" void kernel_launch(void* const* d_in, const int* in_sizes, int n_in,
                              void* d_out, int out_size, void* d_ws, size_t ws_size,
                              hipStream_t stream)
{
    const float* x      = (const float*)d_in[0];
    const float* W_emb  = (const float*)d_in[1];
    const float* b_emb  = (const float*)d_in[2];
    const float* g_emb  = (const float*)d_in[3];
    const float* be_emb = (const float*)d_in[4];
    const float* cls    = (const float*)d_in[5];
    const float* pos    = (const float*)d_in[6];
    const float* ln1_g  = (const float*)d_in[7];
    const float* ln1_b  = (const float*)d_in[8];
    const float* Wq     = (const float*)d_in[9];
    const float* bq     = (const float*)d_in[10];
    const float* Wk     = (const float*)d_in[11];
    const float* bk     = (const float*)d_in[12];
    const float* Wv     = (const float*)d_in[13];
    const float* bv     = (const float*)d_in[14];
    const float* Wo     = (const float*)d_in[15];
    const float* bo     = (const float*)d_in[16];
    const float* ln2_g  = (const float*)d_in[17];
    const float* ln2_b  = (const float*)d_in[18];
    const float* W1     = (const float*)d_in[19];
    const float* b1     = (const float*)d_in[20];
    const float* W2     = (const float*)d_in[21];
    const float* b2     = (const float*)d_in[22];
    const float* Wc1    = (const float*)d_in[23];
    const float* bc1    = (const float*)d_in[24];
    const float* lnc_g  = (const float*)d_in[25];
    const float* lnc_b  = (const float*)d_in[26];
    const float* Wc2    = (const float*)d_in[27];
    const float* bc2    = (const float*)d_in[28];
    float* out = (float*)d_out;

    char* p = (char*)d_ws;
    float* h    = (float*)p; p += (long)M_ * 256 * 4;
    bf16* y     = (bf16*)p;  p += (long)M_ * 256 * 2;
    bf16* qkv   = (bf16*)p;  p += (long)M_ * 768 * 2;
    bf16* obuf  = (bf16*)p;  p += (long)M_ * 256 * 2;
    bf16* tb    = (bf16*)p;  p += (long)M_ * 1024 * 2;
    bf16* Wqkvt = (bf16*)p;  p += (long)L_ * 768 * 256 * 2;
    bf16* Wot   = (bf16*)p;  p += (long)L_ * 256 * 256 * 2;
    bf16* W1t   = (bf16*)p;  p += (long)L_ * 1024 * 256 * 2;
    bf16* W2t   = (bf16*)p;  p += (long)L_ * 256 * 1024 * 2;
    float* bqkv = (float*)p; p += (long)L_ * 768 * 4;
    float* pool = (float*)p; p += (long)B_ * 16 * 256 * 4;

    // ---- weight packing (4 launches) ----
    pack_qkv_t<<<dim3(24, 8, L_), 256, 0, stream>>>(Wq, Wk, Wv, bq, bk, bv, Wqkvt, bqkv);
    pack_wt_t<<<dim3(8, 8, L_),  256, 0, stream>>>(Wo, Wot, 256, 256);
    pack_wt_t<<<dim3(32, 8, L_), 256, 0, stream>>>(W1, W1t, 256, 1024);
    pack_wt_t<<<dim3(8, 32, L_), 256, 0, stream>>>(W2, W2t, 1024, 256);

    embed4_kernel<<<M_ / 4, 256, 0, stream>>>(x, W_emb, b_emb, g_emb, be_emb, cls, h);

    dim3 gQKV(6, 65), gMLP1(8, 65), gEE(4, 129);
    for (int l = 0; l < L_; ++l) {
        ln4_kernel<<<M_ / 4, 256, 0, stream>>>(h, pos, ln1_g + l * E_, ln1_b + l * E_, y);
        gemm_bf16_128<<<gQKV, 256, 0, stream>>>(y, Wqkvt + (long)l * 768 * 256, bqkv + l * 768,
                                                nullptr, qkv, M_, 256, 768, 0);
        attn_mfma_kernel<<<B_ * H_ * NQT, 256, 0, stream>>>(qkv, obuf);
        gemm_bf16<<<gEE, 256, 0, stream>>>(obuf, Wot + (long)l * 65536, bo + l * E_,
                                           h, h, nullptr, M_, 256, 256, 0);
        ln4_kernel<<<M_ / 4, 256, 0, stream>>>(h, nullptr, ln2_g + l * E_, ln2_b + l * E_, y);
        gemm_bf16_128<<<gMLP1, 256, 0, stream>>>(y, W1t + (long)l * 262144, b1 + l * XE_,
                                                 nullptr, tb, M_, 256, 1024, 1);
        gemm_bf16<<<gEE, 256, 0, stream>>>(tb, W2t + (long)l * 262144, b2 + l * E_,
                                           h, h, nullptr, M_, 1024, 256, 0);
    }

    pool_kernel<<<B_ * 16, 256, 0, stream>>>(h, pool);
    cls_final<<<B_, 256, 0, stream>>>(pool, Wc1, bc1, lnc_g, lnc_b, Wc2, bc2, out);
}